// Round 2
// baseline (477.760 us; speedup 1.0000x reference)
//
#include <hip/hip_runtime.h>
#include <math.h>

#define N_NODES 90
#define KSEL 45
#define DIM 1024
#define BATCH 512
#define NROWS (BATCH * N_NODES)   // 46080
#define MROWS (BATCH * KSEL)      // 23040

#define DOT4(p, q) ((p).x*(q).x + (p).y*(q).y + (p).z*(q).z + (p).w*(q).w)

// ---------------------------------------------------------------------------
// Kernel A: wave-per-row scores, grid-stride. Each lane holds 16 floats of
// the row (4×float4, coalesced [j*64+lane]) from each tensor → 8 loads in
// flight. pool_w fragment + ||w|| hoisted out of the row loop.
// ---------------------------------------------------------------------------
__global__ __launch_bounds__(256) void score_kernel(
    const float* __restrict__ x_sc, const float* __restrict__ x_fc,
    const float* __restrict__ pool_w, const float* __restrict__ multi_w,
    const float* __restrict__ multi_b, float* __restrict__ scores)
{
    const int lane = threadIdx.x & 63;
    const int wid  = (blockIdx.x << 2) | (threadIdx.x >> 6);
    const int nw   = gridDim.x << 2;

    const float4* w4 = (const float4*)pool_w;
    const float4 w0 = w4[lane], w1 = w4[64 + lane],
                 w2 = w4[128 + lane], w3 = w4[192 + lane];

    float wsq = DOT4(w0, w0) + DOT4(w1, w1) + DOT4(w2, w2) + DOT4(w3, w3);
    #pragma unroll
    for (int off = 32; off; off >>= 1) wsq += __shfl_down(wsq, off, 64);
    const float inv_norm = rsqrtf(__shfl(wsq, 0, 64));
    const float mw0 = multi_w[0], mw1 = multi_w[1];

    for (int row = wid; row < NROWS; row += nw) {
        const float4* a4 = (const float4*)(x_sc + (size_t)row * DIM);
        const float4* b4 = (const float4*)(x_fc + (size_t)row * DIM);
        float4 a0 = a4[lane], a1 = a4[64 + lane],
               a2 = a4[128 + lane], a3 = a4[192 + lane];
        float4 c0 = b4[lane], c1 = b4[64 + lane],
               c2 = b4[128 + lane], c3 = b4[192 + lane];

        float dsc = DOT4(a0, w0) + DOT4(a1, w1) + DOT4(a2, w2) + DOT4(a3, w3);
        float dfc = DOT4(c0, w0) + DOT4(c1, w1) + DOT4(c2, w2) + DOT4(c3, w3);

        #pragma unroll
        for (int off = 32; off; off >>= 1) {
            dsc += __shfl_down(dsc, off, 64);
            dfc += __shfl_down(dfc, off, 64);
        }
        if (lane == 0) {
            float sc = tanhf(dsc * inv_norm);
            float fc = tanhf(dfc * inv_norm);
            float z = sc * mw0 + fc * mw1 + multi_b[row % N_NODES];
            scores[row] = 1.0f / (1.0f + expf(-z));
        }
    }
}

// ---------------------------------------------------------------------------
// Kernel B: stable top-K per batch (rank-by-counting == argsort(-s) stable).
// ---------------------------------------------------------------------------
__global__ __launch_bounds__(128) void topk_kernel(
    const float* __restrict__ scores, int* __restrict__ idx,
    float* __restrict__ wgt)
{
    const int b = blockIdx.x;
    const int t = threadIdx.x;
    __shared__ float s[N_NODES];
    if (t < N_NODES) s[t] = scores[b * N_NODES + t];
    __syncthreads();
    if (t < N_NODES) {
        float v = s[t];
        int rank = 0;
        #pragma unroll
        for (int j = 0; j < N_NODES; ++j) {
            float u = s[j];
            rank += (u > v) || (u == v && j < t);
        }
        if (rank < KSEL) {
            idx[b * KSEL + rank] = t;
            wgt[b * KSEL + rank] = v;
        }
    }
}

// ---------------------------------------------------------------------------
// Kernel C: gather+scale, wave-per-output-row, grid-stride. 8 loads in
// flight per lane, coalesced loads and stores.
// ---------------------------------------------------------------------------
__global__ __launch_bounds__(256) void gather_kernel(
    const float* __restrict__ x_sc, const float* __restrict__ x_fc,
    const int* __restrict__ idx, const float* __restrict__ wgt,
    float* __restrict__ out)
{
    const int lane = threadIdx.x & 63;
    const int wid  = (blockIdx.x << 2) | (threadIdx.x >> 6);
    const int nw   = gridDim.x << 2;
    const size_t OUT2 = (size_t)MROWS * DIM;

    for (int m = wid; m < MROWS; m += nw) {
        const int b = m / KSEL;
        const int n = idx[m];
        const float w = wgt[m];
        const size_t src = ((size_t)b * N_NODES + n) * DIM;

        const float4* a4 = (const float4*)(x_sc + src);
        const float4* b4 = (const float4*)(x_fc + src);
        float4* o1 = (float4*)(out + (size_t)m * DIM);
        float4* o2 = (float4*)(out + OUT2 + (size_t)m * DIM);

        float4 a0 = a4[lane], a1 = a4[64 + lane],
               a2 = a4[128 + lane], a3 = a4[192 + lane];
        float4 c0 = b4[lane], c1 = b4[64 + lane],
               c2 = b4[128 + lane], c3 = b4[192 + lane];

        a0.x *= w; a0.y *= w; a0.z *= w; a0.w *= w;
        a1.x *= w; a1.y *= w; a1.z *= w; a1.w *= w;
        a2.x *= w; a2.y *= w; a2.z *= w; a2.w *= w;
        a3.x *= w; a3.y *= w; a3.z *= w; a3.w *= w;
        c0.x *= w; c0.y *= w; c0.z *= w; c0.w *= w;
        c1.x *= w; c1.y *= w; c1.z *= w; c1.w *= w;
        c2.x *= w; c2.y *= w; c2.z *= w; c2.w *= w;
        c3.x *= w; c3.y *= w; c3.z *= w; c3.w *= w;

        o1[lane] = a0; o1[64 + lane] = a1; o1[128 + lane] = a2; o1[192 + lane] = a3;
        o2[lane] = c0; o2[64 + lane] = c1; o2[128 + lane] = c2; o2[192 + lane] = c3;
    }
}

extern "C" void kernel_launch(void* const* d_in, const int* in_sizes, int n_in,
                              void* d_out, int out_size, void* d_ws, size_t ws_size,
                              hipStream_t stream) {
    const float* x_sc    = (const float*)d_in[0];
    const float* x_fc    = (const float*)d_in[1];
    const float* pool_w  = (const float*)d_in[2];
    const float* multi_w = (const float*)d_in[3];
    const float* multi_b = (const float*)d_in[4];
    float* out = (float*)d_out;

    float* scores = (float*)d_ws;
    float* wgt    = scores + BATCH * N_NODES;
    int*   idx    = (int*)(wgt + BATCH * KSEL);

    // 2880 blocks * 4 waves = 11520 waves -> 4 rows/wave for score
    score_kernel<<<2880, 256, 0, stream>>>(
        x_sc, x_fc, pool_w, multi_w, multi_b, scores);
    topk_kernel<<<BATCH, 128, 0, stream>>>(scores, idx, wgt);
    // 1440 blocks * 4 waves = 5760 waves -> 4 rows/wave for gather
    gather_kernel<<<1440, 256, 0, stream>>>(
        x_sc, x_fc, idx, wgt, out);
}